// Round 3
// baseline (1108.974 us; speedup 1.0000x reference)
//
#include <hip/hip_runtime.h>
#include <hip/hip_bf16.h>
#include <math.h>

#define DIMM 2048
#define HID  7168
#define MTOK 4096   // B*S
#define SEQ  2048
#define NH   32

typedef unsigned short u16;
typedef __attribute__((ext_vector_type(8))) short short8;
typedef __attribute__((ext_vector_type(4))) float f32x4;

// GEMM-plane swizzle: permute 8-elem chunks within 32-elem K-groups by row bits 1-2.
// Makes the [128][32] LDS tile's ds_read_b128 pattern 2-way (free) instead of 8-way.
__device__ __forceinline__ int swzg(int row, int col) {
    return col ^ (((row >> 1) & 3) << 3);
}
// Attention-plane swizzle: permute 8-elem chunks within 64-elem groups by row bits 0-2.
// Makes the [64][64] LDS tile's fragment reads 2-way instead of 16-way.
__device__ __forceinline__ int swza(int row, int col) {
    return col ^ ((row & 7) << 3);
}
__device__ __forceinline__ u16 f2bf(float v) {
    unsigned u = __float_as_uint(v);
    return (u16)((u + 0x7FFFu + ((u >> 16) & 1u)) >> 16);
}

#define GL16(gp, lp) __builtin_amdgcn_global_load_lds(                         \
    (const __attribute__((address_space(1))) void*)(gp),                       \
    (__attribute__((address_space(3))) void*)(lp), 16, 0, 0)

// ---------------- fp32 [rows,cols] (ld-strided) -> bf16 swzg plane ----------------
__global__ __launch_bounds__(256) void cvt_plane(const float* __restrict__ src,
                                                 u16* __restrict__ dst,
                                                 int cols, int ld) {
    int r = blockIdx.y;
    int c = (blockIdx.x * 256 + threadIdx.x) * 8;
    if (c >= cols) return;
    const float* sp = src + (size_t)r * ld + c;
    float4 a = *(const float4*)sp;
    float4 b = *(const float4*)(sp + 4);
    float o[8] = {a.x, a.y, a.z, a.w, b.x, b.y, b.z, b.w};
    ushort4 h0, h1;
    h0.x = f2bf(o[0]); h0.y = f2bf(o[1]); h0.z = f2bf(o[2]); h0.w = f2bf(o[3]);
    h1.x = f2bf(o[4]); h1.y = f2bf(o[5]); h1.z = f2bf(o[6]); h1.w = f2bf(o[7]);
    size_t base = (size_t)r * cols + swzg(r, c);
    *(ushort4*)&dst[base]     = h0;
    *(ushort4*)&dst[base + 4] = h1;
}

// ---------------- RMSNorm fp32 -> bf16 swzg plane ----------------
__global__ __launch_bounds__(256) void rmsnorm_bf16(const float* __restrict__ x,
                                                    const float* __restrict__ w,
                                                    u16* __restrict__ y) {
    int row = blockIdx.x, tid = threadIdx.x;
    const float* xr = x + (size_t)row * DIMM;
    float4 a = *(const float4*)&xr[tid * 8];
    float4 b = *(const float4*)&xr[tid * 8 + 4];
    float ss = a.x*a.x + a.y*a.y + a.z*a.z + a.w*a.w
             + b.x*b.x + b.y*b.y + b.z*b.z + b.w*b.w;
    #pragma unroll
    for (int m = 1; m < 64; m <<= 1) ss += __shfl_xor(ss, m);
    __shared__ float red[4];
    if ((tid & 63) == 0) red[tid >> 6] = ss;
    __syncthreads();
    float scale = rsqrtf((red[0] + red[1] + red[2] + red[3]) * (1.0f / (float)DIMM) + 1e-6f);
    float4 wa = *(const float4*)&w[tid * 8];
    float4 wb = *(const float4*)&w[tid * 8 + 4];
    float o[8] = { a.x*scale*wa.x, a.y*scale*wa.y, a.z*scale*wa.z, a.w*scale*wa.w,
                   b.x*scale*wb.x, b.y*scale*wb.y, b.z*scale*wb.z, b.w*scale*wb.w };
    ushort4 h0, h1;
    h0.x = f2bf(o[0]); h0.y = f2bf(o[1]); h0.z = f2bf(o[2]); h0.w = f2bf(o[3]);
    h1.x = f2bf(o[4]); h1.y = f2bf(o[5]); h1.z = f2bf(o[6]); h1.w = f2bf(o[7]);
    size_t base = (size_t)row * DIMM + swzg(row, tid * 8);
    *(ushort4*)&y[base]     = h0;
    *(ushort4*)&y[base + 4] = h1;
}

// ---------------- bf16 MFMA GEMM: C[M,N] = A[M,K] @ B[N,K]^T ----------------
// A,B are swzg bf16 planes. 128x128 tile, BK=32, 4 waves (2x2), 4x4 16x16x32 frags.
// EPI 0: Cf = acc + R (fp32)
// EPI 1: Cb[row*N + swza(row,col)] = bf16(acc*scale)      (attention operand plane)
// EPI 2: Cb[col*M + (tok ^ ((col&7)<<3))] = bf16(acc)     (V transposed: vt[d][token])
template<int EPI>
__global__ __launch_bounds__(256, 2) void gemm_bf16(const u16* __restrict__ A,
                                                    const u16* __restrict__ B,
                                                    const float* __restrict__ R,
                                                    float* __restrict__ Cf,
                                                    u16* __restrict__ Cb,
                                                    int M, int N, int K, int ldb,
                                                    float scale) {
    __shared__ u16 sA[128 * 32], sB[128 * 32];
    int tid = threadIdx.x;
    int w = tid >> 6, l = tid & 63;
    int bm = blockIdx.y * 128, bn = blockIdx.x * 128;
    int wm = w >> 1, wn = w & 1;

    int c0 = tid, c1 = tid + 256;
    size_t ga0 = (size_t)(bm + (c0 >> 2)) * K   + ((c0 & 3) << 3);
    size_t ga1 = (size_t)(bm + (c1 >> 2)) * K   + ((c1 & 3) << 3);
    size_t gb0 = (size_t)(bn + (c0 >> 2)) * ldb + ((c0 & 3) << 3);
    size_t gb1 = (size_t)(bn + (c1 >> 2)) * ldb + ((c1 & 3) << 3);
    int lb0 = (w * 64) * 8;
    int lb1 = (256 + w * 64) * 8;

    int fr = l & 15;
    int fg = (l >> 4) * 8;
    int aoffs[4], boffs[4];
    #pragma unroll
    for (int i = 0; i < 4; ++i) {
        int ar = wm * 64 + i * 16 + fr;
        aoffs[i] = ar * 32 + (fg ^ (((ar >> 1) & 3) << 3));
        int br = wn * 64 + i * 16 + fr;
        boffs[i] = br * 32 + (fg ^ (((br >> 1) & 3) << 3));
    }

    f32x4 zero = {0.0f, 0.0f, 0.0f, 0.0f};
    f32x4 acc[4][4];
    #pragma unroll
    for (int i = 0; i < 4; ++i)
        #pragma unroll
        for (int j = 0; j < 4; ++j) acc[i][j] = zero;

    for (int k0 = 0; k0 < K; k0 += 32) {
        __syncthreads();
        GL16(A + ga0 + k0, sA + lb0);
        GL16(A + ga1 + k0, sA + lb1);
        GL16(B + gb0 + k0, sB + lb0);
        GL16(B + gb1 + k0, sB + lb1);
        __syncthreads();
        short8 ah[4], bh[4];
        #pragma unroll
        for (int i = 0; i < 4; ++i) {
            ah[i] = *(const short8*)&sA[aoffs[i]];
            bh[i] = *(const short8*)&sB[boffs[i]];
        }
        #pragma unroll
        for (int i = 0; i < 4; ++i)
            #pragma unroll
            for (int j = 0; j < 4; ++j)
                acc[i][j] = __builtin_amdgcn_mfma_f32_16x16x32_bf16(ah[i], bh[j], acc[i][j], 0, 0, 0);
    }

    // C/D layout (m89): col = lane&15, row = (lane>>4)*4 + reg
    if (EPI == 0) {
        #pragma unroll
        for (int i = 0; i < 4; ++i)
            #pragma unroll
            for (int q = 0; q < 4; ++q) {
                size_t base = (size_t)(bm + wm * 64 + i * 16 + (l >> 4) * 4 + q) * N
                            + bn + wn * 64 + fr;
                #pragma unroll
                for (int j = 0; j < 4; ++j)
                    Cf[base + j * 16] = acc[i][j][q] + R[base + j * 16];
            }
    } else if (EPI == 1) {
        #pragma unroll
        for (int i = 0; i < 4; ++i)
            #pragma unroll
            for (int q = 0; q < 4; ++q) {
                int row = bm + wm * 64 + i * 16 + (l >> 4) * 4 + q;
                #pragma unroll
                for (int j = 0; j < 4; ++j) {
                    int col = bn + wn * 64 + j * 16 + fr;
                    Cb[(size_t)row * N + swza(row, col)] = f2bf(acc[i][j][q] * scale);
                }
            }
    } else {  // EPI == 2: vt[d][token], token bits 3-5 XOR'd by d bits 0-2
        #pragma unroll
        for (int i = 0; i < 4; ++i) {
            int tok0 = bm + wm * 64 + i * 16 + (l >> 4) * 4;
            #pragma unroll
            for (int j = 0; j < 4; ++j) {
                int vd = bn + wn * 64 + j * 16 + fr;
                ushort4 h;
                h.x = f2bf(acc[i][j][0]); h.y = f2bf(acc[i][j][1]);
                h.z = f2bf(acc[i][j][2]); h.w = f2bf(acc[i][j][3]);
                *(ushort4*)&Cb[(size_t)vd * M + (tok0 ^ ((vd & 7) << 3))] = h;
            }
        }
    }
}

// ---------------- fused w1/w3 GEMM + SiLU*mul -> bf16 swzg plane ----------------
__global__ __launch_bounds__(256, 2) void gemm_w13(const u16* __restrict__ A,
                                                   const u16* __restrict__ B1,
                                                   const u16* __restrict__ B3,
                                                   u16* __restrict__ Cb,
                                                   int M, int N, int K) {
    __shared__ u16 sA[128 * 32], sB1[128 * 32], sB3[128 * 32];
    int tid = threadIdx.x;
    int w = tid >> 6, l = tid & 63;
    int bm = blockIdx.y * 128, bn = blockIdx.x * 128;
    int wm = w >> 1, wn = w & 1;

    int c0 = tid, c1 = tid + 256;
    size_t ga0 = (size_t)(bm + (c0 >> 2)) * K + ((c0 & 3) << 3);
    size_t ga1 = (size_t)(bm + (c1 >> 2)) * K + ((c1 & 3) << 3);
    size_t gb0 = (size_t)(bn + (c0 >> 2)) * K + ((c0 & 3) << 3);
    size_t gb1 = (size_t)(bn + (c1 >> 2)) * K + ((c1 & 3) << 3);
    int lb0 = (w * 64) * 8;
    int lb1 = (256 + w * 64) * 8;

    int fr = l & 15;
    int fg = (l >> 4) * 8;
    int aoffs[4], boffs[4];
    #pragma unroll
    for (int i = 0; i < 4; ++i) {
        int ar = wm * 64 + i * 16 + fr;
        aoffs[i] = ar * 32 + (fg ^ (((ar >> 1) & 3) << 3));
        int br = wn * 64 + i * 16 + fr;
        boffs[i] = br * 32 + (fg ^ (((br >> 1) & 3) << 3));
    }

    f32x4 zero = {0.0f, 0.0f, 0.0f, 0.0f};
    f32x4 acc1[4][4], acc3[4][4];
    #pragma unroll
    for (int i = 0; i < 4; ++i)
        #pragma unroll
        for (int j = 0; j < 4; ++j) { acc1[i][j] = zero; acc3[i][j] = zero; }

    for (int k0 = 0; k0 < K; k0 += 32) {
        __syncthreads();
        GL16(A  + ga0 + k0, sA  + lb0);
        GL16(A  + ga1 + k0, sA  + lb1);
        GL16(B1 + gb0 + k0, sB1 + lb0);
        GL16(B1 + gb1 + k0, sB1 + lb1);
        GL16(B3 + gb0 + k0, sB3 + lb0);
        GL16(B3 + gb1 + k0, sB3 + lb1);
        __syncthreads();
        short8 ah[4];
        #pragma unroll
        for (int i = 0; i < 4; ++i) ah[i] = *(const short8*)&sA[aoffs[i]];
        #pragma unroll
        for (int j = 0; j < 4; ++j) {
            short8 b1 = *(const short8*)&sB1[boffs[j]];
            short8 b3 = *(const short8*)&sB3[boffs[j]];
            #pragma unroll
            for (int i = 0; i < 4; ++i) {
                acc1[i][j] = __builtin_amdgcn_mfma_f32_16x16x32_bf16(ah[i], b1, acc1[i][j], 0, 0, 0);
                acc3[i][j] = __builtin_amdgcn_mfma_f32_16x16x32_bf16(ah[i], b3, acc3[i][j], 0, 0, 0);
            }
        }
    }

    #pragma unroll
    for (int i = 0; i < 4; ++i)
        #pragma unroll
        for (int q = 0; q < 4; ++q) {
            int row = bm + wm * 64 + i * 16 + (l >> 4) * 4 + q;
            #pragma unroll
            for (int j = 0; j < 4; ++j) {
                int col = bn + wn * 64 + j * 16 + fr;
                float g = acc1[i][j][q];
                float v = g / (1.0f + __expf(-g)) * acc3[i][j][q];
                Cb[(size_t)row * N + swzg(row, col)] = f2bf(v);
            }
        }
}

// ---------------- MFMA flash attention (non-causal, GQA) ----------------
// qp: [MTOK,2048] bf16 swza (pre-scaled by 0.125); kp: [MTOK,512] bf16 swza;
// vt: [512,MTOK] bf16, token bits 3-5 ^ (d&7)<<3; op: [MTOK,2048] bf16 swzg out.
// Block: 256 thr = 4 waves; Q-tile 64 rows, wave w owns rows w*16..w*16+15.
__global__ __launch_bounds__(256, 2) void attn_mfma(const u16* __restrict__ qp,
                                                    const u16* __restrict__ kp,
                                                    const u16* __restrict__ vt,
                                                    u16* __restrict__ op) {
    __shared__ u16 Qs[64 * 64], Ks[64 * 64], Vs[64 * 64], Ps[4][16 * 64];
    int tid = threadIdx.x;
    int w = tid >> 6, l = tid & 63;
    int qt = blockIdx.x, bh = blockIdx.y;
    int b = bh >> 5, h = bh & 31, kvh = h >> 2;
    int qrow0 = b * SEQ + qt * 64;
    int qcol = h * 64, kcol = kvh * 64;

    // ---- stage Q tile [64 q][64 d] (8 chunks/row) ----
    {
        int cA = tid, cB = tid + 256;
        GL16(qp + (size_t)(qrow0 + (cA >> 3)) * DIMM + qcol + ((cA & 7) << 3), Qs + (w * 64) * 8);
        GL16(qp + (size_t)(qrow0 + (cB >> 3)) * DIMM + qcol + ((cB & 7) << 3), Qs + (256 + w * 64) * 8);
    }
    __syncthreads();
    int fr = l & 15, fg = (l >> 4) * 8;
    int qr = w * 16 + fr;
    short8 qa0 = *(const short8*)&Qs[qr * 64 + (fg ^ ((qr & 7) << 3))];
    short8 qa1 = *(const short8*)&Qs[qr * 64 + ((32 + fg) ^ ((qr & 7) << 3))];

    // ---- precomputed LDS addresses ----
    u16* Pw = Ps[w];
    int pwa[4][4], kfa[4][2], pra[2];
    #pragma unroll
    for (int qi = 0; qi < 4; ++qi) {
        int qloc = (l >> 4) * 4 + qi;
        #pragma unroll
        for (int nj = 0; nj < 4; ++nj)
            pwa[qi][nj] = qloc * 64 + ((nj * 16 + fr) ^ ((qloc & 7) << 3));
    }
    #pragma unroll
    for (int nj = 0; nj < 4; ++nj) {
        int r = nj * 16 + fr;
        kfa[nj][0] = r * 64 + (fg ^ ((r & 7) << 3));
        kfa[nj][1] = r * 64 + ((32 + fg) ^ ((r & 7) << 3));
    }
    pra[0] = fr * 64 + (fg ^ ((fr & 7) << 3));
    pra[1] = fr * 64 + ((32 + fg) ^ ((fr & 7) << 3));

    // ---- staging source offsets (advance by tile inside loop) ----
    int cA = tid, cB = tid + 256;
    size_t gk0 = (size_t)(b * SEQ + (cA >> 3)) * 512 + kcol + ((cA & 7) << 3);
    size_t gk1 = (size_t)(b * SEQ + (cB >> 3)) * 512 + kcol + ((cB & 7) << 3);
    size_t gv0 = (size_t)(kvh * 64 + (cA >> 3)) * (size_t)MTOK + b * SEQ + ((cA & 7) << 3);
    size_t gv1 = (size_t)(kvh * 64 + (cB >> 3)) * (size_t)MTOK + b * SEQ + ((cB & 7) << 3);

    f32x4 zero = {0.0f, 0.0f, 0.0f, 0.0f};
    f32x4 oa[4];
    #pragma unroll
    for (int dj = 0; dj < 4; ++dj) oa[dj] = zero;
    float m_run[4] = {-1e30f, -1e30f, -1e30f, -1e30f};
    float l_run[4] = {0.0f, 0.0f, 0.0f, 0.0f};

    for (int kt = 0; kt < SEQ / 64; ++kt) {
        __syncthreads();
        GL16(kp + gk0 + (size_t)kt * 64 * 512, Ks + (w * 64) * 8);
        GL16(kp + gk1 + (size_t)kt * 64 * 512, Ks + (256 + w * 64) * 8);
        GL16(vt + gv0 + (size_t)kt * 64,       Vs + (w * 64) * 8);
        GL16(vt + gv1 + (size_t)kt * 64,       Vs + (256 + w * 64) * 8);
        __syncthreads();

        // S = Q @ K^T  (Q pre-scaled by 1/8)
        f32x4 sacc[4];
        #pragma unroll
        for (int nj = 0; nj < 4; ++nj) {
            short8 kb0 = *(const short8*)&Ks[kfa[nj][0]];
            short8 kb1 = *(const short8*)&Ks[kfa[nj][1]];
            sacc[nj] = __builtin_amdgcn_mfma_f32_16x16x32_bf16(qa0, kb0, zero, 0, 0, 0);
            sacc[nj] = __builtin_amdgcn_mfma_f32_16x16x32_bf16(qa1, kb1, sacc[nj], 0, 0, 0);
        }

        // online softmax: rows = (l>>4)*4 + qi, cols spread over 16 lanes x 4 nj
        float rs[4];
        #pragma unroll
        for (int qi = 0; qi < 4; ++qi) {
            float tm = fmaxf(fmaxf(sacc[0][qi], sacc[1][qi]), fmaxf(sacc[2][qi], sacc[3][qi]));
            #pragma unroll
            for (int m = 1; m < 16; m <<= 1) tm = fmaxf(tm, __shfl_xor(tm, m));
            float mnew = fmaxf(m_run[qi], tm);
            rs[qi] = __expf(m_run[qi] - mnew);
            float ps = 0.0f;
            #pragma unroll
            for (int nj = 0; nj < 4; ++nj) {
                float p = __expf(sacc[nj][qi] - mnew);
                sacc[nj][qi] = p; ps += p;
            }
            #pragma unroll
            for (int m = 1; m < 16; m <<= 1) ps += __shfl_xor(ps, m);
            l_run[qi] = l_run[qi] * rs[qi] + ps;
            m_run[qi] = mnew;
        }

        // P -> wave-private LDS (bf16, swizzled, transposed to A-layout)
        #pragma unroll
        for (int qi = 0; qi < 4; ++qi)
            #pragma unroll
            for (int nj = 0; nj < 4; ++nj)
                Pw[pwa[qi][nj]] = f2bf(sacc[nj][qi]);
        short8 pa0 = *(const short8*)&Pw[pra[0]];
        short8 pa1 = *(const short8*)&Pw[pra[1]];

        // O = O*rs + P @ V^T
        #pragma unroll
        for (int dj = 0; dj < 4; ++dj) {
            short8 vb0 = *(const short8*)&Vs[kfa[dj][0]];
            short8 vb1 = *(const short8*)&Vs[kfa[dj][1]];
            f32x4 o = oa[dj];
            o[0] *= rs[0]; o[1] *= rs[1]; o[2] *= rs[2]; o[3] *= rs[3];
            o = __builtin_amdgcn_mfma_f32_16x16x32_bf16(pa0, vb0, o, 0, 0, 0);
            o = __builtin_amdgcn_mfma_f32_16x16x32_bf16(pa1, vb1, o, 0, 0, 0);
            oa[dj] = o;
        }
    }

    float inv[4];
    #pragma unroll
    for (int qi = 0; qi < 4; ++qi) inv[qi] = 1.0f / l_run[qi];
    #pragma unroll
    for (int dj = 0; dj < 4; ++dj)
        #pragma unroll
        for (int qi = 0; qi < 4; ++qi) {
            int row = qrow0 + w * 16 + (l >> 4) * 4 + qi;
            int col = qcol + dj * 16 + fr;
            op[(size_t)row * DIMM + swzg(row, col)] = f2bf(oa[dj][qi] * inv[qi]);
        }
}

extern "C" void kernel_launch(void* const* d_in, const int* in_sizes, int n_in,
                              void* d_out, int out_size, void* d_ws, size_t ws_size,
                              hipStream_t stream) {
    const float* x   = (const float*)d_in[0];
    const float* wq  = (const float*)d_in[1];
    const float* wk  = (const float*)d_in[2];
    const float* wv  = (const float*)d_in[3];
    const float* wo  = (const float*)d_in[4];
    const float* w1  = (const float*)d_in[5];
    const float* w2  = (const float*)d_in[6];   // dict order: w2 before w3
    const float* w3  = (const float*)d_in[7];
    const float* anw = (const float*)d_in[8];
    const float* fnw = (const float*)d_in[9];
    float* out = (float*)d_out;

    char* W = (char*)d_ws;
    size_t off = 0;
    auto take = [&](size_t bytes) { char* p = W + off; off += (bytes + 255) & ~(size_t)255; return p; };

    u16* xnb = (u16*)take((size_t)MTOK * DIMM * 2);   // xn, reused for hn
    u16* wqb = (u16*)take((size_t)DIMM * DIMM * 2);
    u16* wkb = (u16*)take((size_t)512  * DIMM * 2);
    u16* wvb = (u16*)take((size_t)512  * DIMM * 2);
    u16* wob = (u16*)take((size_t)DIMM * DIMM * 2);
    u16* w1b = (u16*)take((size_t)HID  * DIMM * 2);
    u16* w3b = (u16*)take((size_t)HID  * DIMM * 2);
    u16* w2b = (u16*)take((size_t)DIMM * HID  * 2);
    u16* qbf = (u16*)take((size_t)MTOK * DIMM * 2);
    u16* kbf = (u16*)take((size_t)MTOK * 512 * 2);
    u16* vtb = (u16*)take((size_t)512 * MTOK * 2);
    u16* ath = (u16*)take((size_t)MTOK * DIMM * 2);

    // FFN hidden chunk sized to remaining workspace (fah = [MTOK][ck] bf16)
    size_t avail = (ws_size > off) ? ws_size - off - 4096 : 0;
    int ck = 128;
    const int opts[7] = {7168, 3584, 1792, 1024, 512, 256, 128};
    for (int i = 0; i < 7; ++i)
        if ((size_t)MTOK * opts[i] * 2 <= avail) { ck = opts[i]; break; }
    u16* fah = (u16*)take((size_t)MTOK * ck * 2);

    dim3 blk(256);
    auto cvt = [&](const float* src, int rows, int cols, int ld, u16* dst) {
        cvt_plane<<<dim3((cols + 2047) / 2048, rows), blk, 0, stream>>>(src, dst, cols, ld);
    };

    // weight planes (per call; harness re-poisons ws)
    cvt(wq, DIMM, DIMM, DIMM, wqb);
    cvt(wk, 512,  DIMM, DIMM, wkb);
    cvt(wv, 512,  DIMM, DIMM, wvb);
    cvt(wo, DIMM, DIMM, DIMM, wob);
    cvt(w1, HID,  DIMM, DIMM, w1b);
    cvt(w3, HID,  DIMM, DIMM, w3b);
    cvt(w2, DIMM, HID,  HID,  w2b);

    // 1. xn = rmsnorm(x)
    rmsnorm_bf16<<<dim3(MTOK), blk, 0, stream>>>(x, anw, xnb);
    // 2-4. Q (x0.125, attn-swz), K (attn-swz), V (transposed vt)
    gemm_bf16<1><<<dim3(DIMM / 128, MTOK / 128), blk, 0, stream>>>(xnb, wqb, nullptr, nullptr, qbf, MTOK, DIMM, DIMM, DIMM, 0.125f);
    gemm_bf16<1><<<dim3(512  / 128, MTOK / 128), blk, 0, stream>>>(xnb, wkb, nullptr, nullptr, kbf, MTOK, 512,  DIMM, DIMM, 1.0f);
    gemm_bf16<2><<<dim3(512  / 128, MTOK / 128), blk, 0, stream>>>(xnb, wvb, nullptr, nullptr, vtb, MTOK, 512,  DIMM, DIMM, 1.0f);
    // 5. attention -> ath (bf16 swzg)
    attn_mfma<<<dim3(SEQ / 64, 2 * NH), blk, 0, stream>>>(qbf, kbf, vtb, ath);
    // 6. h = x + attn @ wo^T (fp32 into d_out)
    gemm_bf16<0><<<dim3(DIMM / 128, MTOK / 128), blk, 0, stream>>>(ath, wob, x, out, nullptr, MTOK, DIMM, DIMM, DIMM, 1.0f);
    // 7. hn = rmsnorm(h)
    rmsnorm_bf16<<<dim3(MTOK), blk, 0, stream>>>(out, fnw, xnb);
    // 8. FFN: fah = silu(hn@w1c^T)*(hn@w3c^T); out += fah @ w2c^T
    for (int c0 = 0; c0 < HID; c0 += ck) {
        gemm_w13<<<dim3(ck / 128, MTOK / 128), blk, 0, stream>>>(
            xnb, w1b + (size_t)c0 * DIMM, w3b + (size_t)c0 * DIMM, fah, MTOK, ck, DIMM);
        gemm_bf16<0><<<dim3(DIMM / 128, MTOK / 128), blk, 0, stream>>>(
            fah, w2b + c0, out, out, nullptr, MTOK, DIMM, ck, HID, 1.0f);
    }
}